// Round 1
// baseline (79.494 us; speedup 1.0000x reference)
//
#include <hip/hip_runtime.h>
#include <cmath>

#define B_ 4
#define L_ 8192
#define N_ 16
#define H_ 64

// ---------------------------------------------------------------------------
// Kernel A: per-row segment-reset positions.
// One block per batch row. Inclusive cumsum of the 8192 int64 lengths into
// LDS (int32, sum <= 8192), then per-element binary search (searchsorted
// right) to find its segment; pos[j] = j - excl_csum[seg], 0 past the total.
// ---------------------------------------------------------------------------
__global__ void pos_kernel(const long long* __restrict__ idx,
                           float* __restrict__ pos) {
    __shared__ int csum[L_];
    __shared__ int partial[257];
    const int b   = blockIdx.x;
    const int tid = threadIdx.x;          // 256 threads
    constexpr int CHUNK = L_ / 256;       // 32 lengths per thread

    const long long* row = idx + (size_t)b * L_;

    // local inclusive scan of this thread's chunk
    int local[CHUNK];
    int s = 0;
#pragma unroll
    for (int i = 0; i < CHUNK; ++i) {
        s += (int)row[tid * CHUNK + i];
        local[i] = s;
    }
    partial[tid + 1] = s;
    if (tid == 0) partial[0] = 0;
    __syncthreads();

    // serial scan of 256 per-thread totals (trivial cost)
    if (tid == 0) {
        int acc = 0;
        for (int i = 1; i <= 256; ++i) { acc += partial[i]; partial[i] = acc; }
    }
    __syncthreads();

    const int off = partial[tid];
#pragma unroll
    for (int i = 0; i < CHUNK; ++i) csum[tid * CHUNK + i] = off + local[i];
    __syncthreads();

    const int total = csum[L_ - 1];

    for (int j = tid; j < L_; j += 256) {
        float p = 0.f;
        if (j < total) {
            // first index with csum[idx] > j  (searchsorted side='right')
            int lo = 0, hi = L_ - 1;
            while (lo < hi) {
                int mid = (lo + hi) >> 1;
                if (csum[mid] > j) hi = mid; else lo = mid + 1;
            }
            const int excl = lo ? csum[lo - 1] : 0;   // segment start offset
            p = (float)(j - excl);
        }
        pos[(size_t)b * L_ + j] = p;
    }
}

// ---------------------------------------------------------------------------
// Kernel B: streaming RoPE. Each thread handles 4 rotation pairs:
// float4 at h in [4q, 4q+4) and the paired float4 at h+32.
//   out[h]    = x[h]*cos - x[h+32]*sin
//   out[h+32] = x[h+32]*cos + x[h]*sin
// cos/sin recomputed per head (VALU is ~20x under the HBM roofline here).
// ---------------------------------------------------------------------------
__global__ void rope_kernel(const float* __restrict__ x,
                            const float* __restrict__ pos,
                            float* __restrict__ out) {
    const size_t t   = (size_t)blockIdx.x * blockDim.x + threadIdx.x;
    const int    q   = (int)(t & 7);      // which quad of the 32 pairs
    const size_t vec = t >> 3;            // (b*L + l)*N + n
    const size_t bl  = vec >> 4;          // b*L + l

    const float p = pos[bl];

    const size_t base = vec * H_ + (size_t)(q * 4);
    const float4 a  = *(const float4*)(x + base);        // x1 part
    const float4 c2 = *(const float4*)(x + base + 32);   // x2 part

    // inv_freq[k] = 10000^(-k/32) = exp(-k * ln(10000)/32)
    constexpr float NEG_LN_BASE_OVER_32 = -0.28782314f;  // -ln(10000)/32

    float4 o1, o2;
    const float k0 = (float)(q * 4);
#pragma unroll
    for (int j = 0; j < 4; ++j) {
        const float f = __expf((k0 + (float)j) * NEG_LN_BASE_OVER_32);
        float sv, cv;
        sincosf(p * f, &sv, &cv);
        const float xa = (&a.x)[j];
        const float xb = (&c2.x)[j];
        (&o1.x)[j] = xa * cv - xb * sv;
        (&o2.x)[j] = xb * cv + xa * sv;
    }

    *(float4*)(out + base)      = o1;
    *(float4*)(out + base + 32) = o2;
}

extern "C" void kernel_launch(void* const* d_in, const int* in_sizes, int n_in,
                              void* d_out, int out_size, void* d_ws, size_t ws_size,
                              hipStream_t stream) {
    const float*     x   = (const float*)d_in[0];
    const long long* idx = (const long long*)d_in[1];
    float*           out = (float*)d_out;
    float*           pos = (float*)d_ws;   // B_*L_ floats = 128 KiB scratch

    pos_kernel<<<B_, 256, 0, stream>>>(idx, pos);

    const size_t total_threads = (size_t)B_ * L_ * N_ * 8;  // 4,194,304
    const int    blocks        = (int)(total_threads / 256); // 16384
    rope_kernel<<<blocks, 256, 0, stream>>>(x, pos, out);
}